// Round 1
// baseline (423.151 us; speedup 1.0000x reference)
//
#include <hip/hip_runtime.h>
#include <hip/hip_bf16.h>
#include <math.h>

// Problem: attr = labels(1024x50000 f32) @ weight(50000x300 f32); out = attr / (||attr||_2 + 1e-7)
// Strategy: bf16 MFMA GEMM (error ~1e-4 post-normalize, threshold 5.4e-3).
//   k1: weight -> Wt[n][k] bf16, n padded to 320 (zero rows)  [LDS-tiled transpose]
//   k2: split-K MFMA GEMM, atomicAdd fp32 partials into ws accumulator
//   k3: row-wise L2 normalize
typedef __bf16 bf16;
typedef bf16 bf16x8 __attribute__((ext_vector_type(8)));
typedef float f32x4 __attribute__((ext_vector_type(4)));

constexpr int Mdim = 1024;
constexpr int Kdim = 50000;
constexpr int Ndim = 300;
constexpr int NP   = 320;            // padded N

constexpr int BM = 64, BN = 320, BK = 64;
constexpr int BKP = 72;              // LDS row stride (bf16): 144 B -> 16B-aligned, bank-spread
constexpr int MT = Mdim / BM;        // 16 m-tiles
constexpr int SPLIT = 16;            // K splits
constexpr int SEGLEN = 3136;         // 49*BK; last seg = 2960

__device__ __forceinline__ bf16x8 bzero8() {
    bf16x8 v;
#pragma unroll
    for (int e = 0; e < 8; ++e) v[e] = (bf16)0.0f;
    return v;
}

// ---------------- k1: transpose + f32->bf16 convert -------------------------
constexpr int TK = 64; // k-tile per block
__global__ __launch_bounds__(256) void transpose_w(const float* __restrict__ W,
                                                   bf16* __restrict__ Wt)
{
    __shared__ bf16 tile[NP * BKP];          // 46080 B, [n][kk] stride 72
    const int k0 = blockIdx.x * TK;
    const int t  = threadIdx.x;

    // load 64 rows x 300 floats, coalesced float4 (300 = 75*4 exactly)
    for (int c = t; c < 64 * 75; c += 256) {
        const int kk = c / 75;
        const int ch = c % 75;
        const int k  = k0 + kk;
        float4 v = make_float4(0.f, 0.f, 0.f, 0.f);
        if (k < Kdim) v = *(const float4*)(W + (size_t)k * Ndim + ch * 4);
        const int n = ch * 4;
        tile[(n + 0) * BKP + kk] = (bf16)v.x;
        tile[(n + 1) * BKP + kk] = (bf16)v.y;
        tile[(n + 2) * BKP + kk] = (bf16)v.z;
        tile[(n + 3) * BKP + kk] = (bf16)v.w;
    }
    __syncthreads();
    // store Wt[n][k], 16B chunks; rows n>=300 are zero padding
    for (int c = t; c < NP * 8; c += 256) {
        const int n  = c >> 3;
        const int ch = c & 7;
        const int k  = k0 + ch * 8;
        if (k + 8 <= Kdim) {                  // tail (16) is chunk-granular: ok
            bf16x8 v;
            if (n < Ndim) v = *(const bf16x8*)(&tile[n * BKP + ch * 8]);
            else          v = bzero8();
            *(bf16x8*)(Wt + (size_t)n * Kdim + k) = v;
        }
    }
}

// ---------------- k2: split-K MFMA GEMM -------------------------------------
__global__ __launch_bounds__(512) void gemm_kernel(const float* __restrict__ A,
                                                   const bf16* __restrict__ Wt,
                                                   float* __restrict__ Cacc)
{
    __shared__ bf16 As[BM * BKP];   //  9216 B
    __shared__ bf16 Bs[BN * BKP];   // 46080 B

    const int bx   = blockIdx.x;
    const int mt   = bx & (MT - 1);
    const int ks   = bx >> 4;
    const int m0   = mt * BM;
    const int kbeg = ks * SEGLEN;
    const int kend = min(kbeg + SEGLEN, Kdim);

    const int t    = threadIdx.x;
    const int lane = t & 63;
    const int wave = t >> 6;        // 0..7
    const int wm   = wave >> 2;     // 0..1 -> m offset wm*32
    const int wn   = wave & 3;      // 0..3 -> n offset wn*80
    const int lm   = lane & 15;
    const int lq   = lane >> 4;

    // A staging: thread -> (row, 8 consecutive k)
    const int arow = t >> 3;        // 0..63
    const int acol = (t & 7) * 8;   // 0..56
    const float* aptr = A + (size_t)(m0 + arow) * Kdim;

    f32x4 acc[2][5] = {};

    for (int k0 = kbeg; k0 < kend; k0 += BK) {
        __syncthreads();
        // ---- stage A: 64x64 f32 -> bf16 (one b128 write per thread)
        {
            const int k = k0 + acol;
            bf16x8 v = bzero8();
            if (k + 8 <= kend) {    // kend-k0 is a multiple of 8 -> chunk-granular
                float4 f0 = *(const float4*)(aptr + k);
                float4 f1 = *(const float4*)(aptr + k + 4);
                v[0] = (bf16)f0.x; v[1] = (bf16)f0.y; v[2] = (bf16)f0.z; v[3] = (bf16)f0.w;
                v[4] = (bf16)f1.x; v[5] = (bf16)f1.y; v[6] = (bf16)f1.z; v[7] = (bf16)f1.w;
            }
            *(bf16x8*)(&As[arow * BKP + acol]) = v;
        }
        // ---- stage B: 320x64 bf16 copy (5 b128 per thread)
#pragma unroll
        for (int i = 0; i < 5; ++i) {
            const int c    = t + 512 * i;
            const int brow = c >> 3;        // 0..319
            const int bcol = (c & 7) * 8;
            const int k    = k0 + bcol;
            bf16x8 v = bzero8();
            if (k + 8 <= kend)
                v = *(const bf16x8*)(Wt + (size_t)brow * Kdim + k);
            *(bf16x8*)(&Bs[brow * BKP + bcol]) = v;
        }
        __syncthreads();
        // ---- MFMA: 2 k-steps of 32, wave tile 32m x 80n
#pragma unroll
        for (int s = 0; s < 2; ++s) {
            bf16x8 a[2], b[5];
#pragma unroll
            for (int i = 0; i < 2; ++i)
                a[i] = *(const bf16x8*)(&As[(wm * 32 + i * 16 + lm) * BKP + s * 32 + lq * 8]);
#pragma unroll
            for (int j = 0; j < 5; ++j)
                b[j] = *(const bf16x8*)(&Bs[(wn * 80 + j * 16 + lm) * BKP + s * 32 + lq * 8]);
#pragma unroll
            for (int i = 0; i < 2; ++i)
#pragma unroll
                for (int j = 0; j < 5; ++j)
                    acc[i][j] = __builtin_amdgcn_mfma_f32_16x16x32_bf16(a[i], b[j], acc[i][j], 0, 0, 0);
        }
    }

    // epilogue: C/D layout col=lane&15, row=(lane>>4)*4+r  [learn_hip m89]
    const int col0 = wn * 80 + lm;
    const int row0 = m0 + wm * 32 + lq * 4;
#pragma unroll
    for (int i = 0; i < 2; ++i)
#pragma unroll
        for (int j = 0; j < 5; ++j)
#pragma unroll
            for (int r = 0; r < 4; ++r)
                atomicAdd(&Cacc[(size_t)(row0 + i * 16 + r) * NP + col0 + j * 16],
                          acc[i][j][r]);
}

// ---------------- k3: row L2 normalize --------------------------------------
__global__ __launch_bounds__(320) void normalize_k(const float* __restrict__ Cacc,
                                                   float* __restrict__ out)
{
    const int b = blockIdx.x;
    const int t = threadIdx.x;
    float v = 0.f;
    if (t < Ndim) v = Cacc[(size_t)b * NP + t];
    float ss = v * v;
#pragma unroll
    for (int o = 32; o > 0; o >>= 1) ss += __shfl_down(ss, o, 64);
    __shared__ float wsum[5];
    __shared__ float scale;
    if ((t & 63) == 0) wsum[t >> 6] = ss;
    __syncthreads();
    if (t == 0) {
        float s = wsum[0] + wsum[1] + wsum[2] + wsum[3] + wsum[4];
        scale = 1.0f / (sqrtf(s) + 1e-7f);
    }
    __syncthreads();
    if (t < Ndim) out[(size_t)b * Ndim + t] = v * scale;
}

// ---------------- launch ----------------------------------------------------
extern "C" void kernel_launch(void* const* d_in, const int* in_sizes, int n_in,
                              void* d_out, int out_size, void* d_ws, size_t ws_size,
                              hipStream_t stream)
{
    const float* labels = (const float*)d_in[0];   // 1024 x 50000
    const float* weight = (const float*)d_in[1];   // 50000 x 300
    float* out = (float*)d_out;                    // 1024 x 300

    // ws layout: [0, 1.31MB) fp32 accumulator (1024x320); then Wt bf16 (320x50000, 32MB)
    float* Cacc = (float*)d_ws;
    bf16*  Wt   = (bf16*)((char*)d_ws + (size_t)Mdim * NP * sizeof(float));

    hipMemsetAsync(Cacc, 0, (size_t)Mdim * NP * sizeof(float), stream);
    transpose_w<<<dim3((Kdim + TK - 1) / TK), dim3(256), 0, stream>>>(weight, Wt);
    gemm_kernel<<<dim3(MT * SPLIT), dim3(512), 0, stream>>>(labels, Wt, Cacc);
    normalize_k<<<dim3(Mdim), dim3(320), 0, stream>>>(Cacc, out);
}

// Round 2
// 391.972 us; speedup vs baseline: 1.0795x; 1.0795x over previous
//
#include <hip/hip_runtime.h>
#include <hip/hip_bf16.h>
#include <math.h>

// attr = labels(1024x50000 f32) @ weight(50000x300 f32); out = attr/(||attr||+1e-7)
// k1: weight -> Wt[n][k] bf16 (n padded to 320) -- conflict-free LDS transpose
// k2: split-K MFMA GEMM, BM=128 BN=320 BK=64, reg-prefetch pipeline, atomic partials
// k3: row L2 normalize
typedef __bf16 bf16;
typedef bf16 bf16x8 __attribute__((ext_vector_type(8)));
typedef float f32x4 __attribute__((ext_vector_type(4)));

constexpr int Mdim = 1024;
constexpr int Kdim = 50000;
constexpr int Ndim = 300;
constexpr int NP   = 320;

constexpr int BM = 128, BN = 320, BK = 64;
constexpr int BKP = 72;            // LDS k-stride (bf16): odd-multiple-of-8 words -> spread banks
constexpr int MT = Mdim / BM;      // 8 m-tiles
constexpr int SPLIT = 32;
constexpr int SEGLEN = 1600;       // 31*1600=49600, last seg = 400

__device__ __forceinline__ bf16x8 bzero8() {
    bf16x8 v;
#pragma unroll
    for (int e = 0; e < 8; ++e) v[e] = (bf16)0.0f;
    return v;
}

// ---------------- k1: transpose + convert -----------------------------------
// LDS tile[kk][n] natural layout, stride 301 (odd) -> phase-2 strided reads hit
// all banks. Phase 1 coalesced float4 reads; phase 2 coalesced b128 writes.
constexpr int TK = 64;
constexpr int TS = 301;            // bf16 elements per kk-row
__global__ __launch_bounds__(256) void transpose_w(const float* __restrict__ W,
                                                   bf16* __restrict__ Wt)
{
    __shared__ bf16 tile[TK * TS];           // 38528 B
    const int k0 = blockIdx.x * TK;
    const int t  = threadIdx.x;

    for (int c = t; c < 64 * 75; c += 256) {
        const int kk = c / 75;
        const int ch = c % 75;
        const int k  = k0 + kk;
        float4 v = make_float4(0.f, 0.f, 0.f, 0.f);
        if (k < Kdim) v = *(const float4*)(W + (size_t)k * Ndim + ch * 4);
        bf16* p = &tile[kk * TS + ch * 4];
        p[0] = (bf16)v.x; p[1] = (bf16)v.y; p[2] = (bf16)v.z; p[3] = (bf16)v.w;
    }
    __syncthreads();
    // Wt[n][k0+ch*8 .. +8): gather 8 kk's (stride TS) for fixed n
    for (int c = t; c < NP * 8; c += 256) {
        const int n  = c >> 3;
        const int ch = c & 7;
        const int k  = k0 + ch * 8;
        if (k + 8 <= Kdim) {                 // Kdim%8==0 -> chunk-granular tail
            bf16x8 v = bzero8();
            if (n < Ndim) {
#pragma unroll
                for (int j = 0; j < 8; ++j) v[j] = tile[(ch * 8 + j) * TS + n];
            }
            *(bf16x8*)(Wt + (size_t)n * Kdim + k) = v;
        }
    }
}

// ---------------- k2: split-K MFMA GEMM -------------------------------------
__global__ __launch_bounds__(512) void gemm_kernel(const float* __restrict__ A,
                                                   const bf16* __restrict__ Wt,
                                                   float* __restrict__ Cacc)
{
    __shared__ bf16 As[BM * BKP];   // 18432 B
    __shared__ bf16 Bs[BN * BKP];   // 46080 B  (total 63 KB)

    const int bx   = blockIdx.x;
    const int mt   = bx & (MT - 1);
    const int ks   = bx >> 3;
    const int m0   = mt * BM;
    const int kbeg = ks * SEGLEN;
    const int kend = min(kbeg + SEGLEN, Kdim);

    const int t    = threadIdx.x;
    const int lane = t & 63;
    const int wave = t >> 6;         // 0..7 as 2m x 4n
    const int wm   = wave >> 2;      // m offset wm*64
    const int wn   = wave & 3;       // n offset wn*80
    const int lm   = lane & 15;
    const int lq   = lane >> 4;

    // A staging: thread -> row t>>2 (0..127), 16 consecutive k at (t&3)*16
    const int arow = t >> 2;
    const int acol = (t & 3) * 16;
    const float* aptr = A + (size_t)(m0 + arow) * Kdim;

    float4 af[4];
    bf16x8 bfr[5];

    auto load_tiles = [&](int k0) {
#pragma unroll
        for (int i = 0; i < 4; ++i) {
            const int k = k0 + acol + i * 4;
            af[i] = (k + 4 <= kend) ? *(const float4*)(aptr + k)
                                    : make_float4(0.f, 0.f, 0.f, 0.f);
        }
#pragma unroll
        for (int i = 0; i < 5; ++i) {
            const int c = t + 512 * i;
            const int brow = c >> 3;
            const int bcol = (c & 7) * 8;
            const int k = k0 + bcol;
            bfr[i] = (k + 8 <= kend) ? *(const bf16x8*)(Wt + (size_t)brow * Kdim + k)
                                     : bzero8();
        }
    };
    auto store_tiles = [&]() {
        bf16x8 v0, v1;
        v0[0]=(bf16)af[0].x; v0[1]=(bf16)af[0].y; v0[2]=(bf16)af[0].z; v0[3]=(bf16)af[0].w;
        v0[4]=(bf16)af[1].x; v0[5]=(bf16)af[1].y; v0[6]=(bf16)af[1].z; v0[7]=(bf16)af[1].w;
        v1[0]=(bf16)af[2].x; v1[1]=(bf16)af[2].y; v1[2]=(bf16)af[2].z; v1[3]=(bf16)af[2].w;
        v1[4]=(bf16)af[3].x; v1[5]=(bf16)af[3].y; v1[6]=(bf16)af[3].z; v1[7]=(bf16)af[3].w;
        *(bf16x8*)(&As[arow * BKP + acol])     = v0;
        *(bf16x8*)(&As[arow * BKP + acol + 8]) = v1;
#pragma unroll
        for (int i = 0; i < 5; ++i) {
            const int c = t + 512 * i;
            const int brow = c >> 3;
            const int bcol = (c & 7) * 8;
            *(bf16x8*)(&Bs[brow * BKP + bcol]) = bfr[i];
        }
    };

    f32x4 acc[4][5] = {};

    load_tiles(kbeg);
    for (int k0 = kbeg; k0 < kend; k0 += BK) {
        store_tiles();               // waits vmcnt, regs -> LDS
        __syncthreads();
        if (k0 + BK < kend) load_tiles(k0 + BK);   // in flight across MFMA phase
#pragma unroll
        for (int s = 0; s < 2; ++s) {
            bf16x8 a[4], b[5];
#pragma unroll
            for (int i = 0; i < 4; ++i)
                a[i] = *(const bf16x8*)(&As[(wm * 64 + i * 16 + lm) * BKP + s * 32 + lq * 8]);
#pragma unroll
            for (int j = 0; j < 5; ++j)
                b[j] = *(const bf16x8*)(&Bs[(wn * 80 + j * 16 + lm) * BKP + s * 32 + lq * 8]);
#pragma unroll
            for (int i = 0; i < 4; ++i)
#pragma unroll
                for (int j = 0; j < 5; ++j)
                    acc[i][j] = __builtin_amdgcn_mfma_f32_16x16x32_bf16(a[i], b[j], acc[i][j], 0, 0, 0);
        }
        __syncthreads();             // ds_reads done before next store_tiles
    }

    // C/D layout: col=lane&15, row=(lane>>4)*4+r  [learn_hip m89]
    const int col0 = wn * 80 + lm;
    const int row0 = m0 + wm * 64 + lq * 4;
#pragma unroll
    for (int i = 0; i < 4; ++i)
#pragma unroll
        for (int j = 0; j < 5; ++j)
#pragma unroll
            for (int r = 0; r < 4; ++r)
                atomicAdd(&Cacc[(size_t)(row0 + i * 16 + r) * NP + col0 + j * 16],
                          acc[i][j][r]);
}

// ---------------- k3: row L2 normalize --------------------------------------
__global__ __launch_bounds__(320) void normalize_k(const float* __restrict__ Cacc,
                                                   float* __restrict__ out)
{
    const int b = blockIdx.x;
    const int t = threadIdx.x;
    float v = 0.f;
    if (t < Ndim) v = Cacc[(size_t)b * NP + t];
    float ss = v * v;
#pragma unroll
    for (int o = 32; o > 0; o >>= 1) ss += __shfl_down(ss, o, 64);
    __shared__ float wsum[5];
    __shared__ float scale;
    if ((t & 63) == 0) wsum[t >> 6] = ss;
    __syncthreads();
    if (t == 0) {
        float s = wsum[0] + wsum[1] + wsum[2] + wsum[3] + wsum[4];
        scale = 1.0f / (sqrtf(s) + 1e-7f);
    }
    __syncthreads();
    if (t < Ndim) out[(size_t)b * Ndim + t] = v * scale;
}

// ---------------- launch ----------------------------------------------------
extern "C" void kernel_launch(void* const* d_in, const int* in_sizes, int n_in,
                              void* d_out, int out_size, void* d_ws, size_t ws_size,
                              hipStream_t stream)
{
    const float* labels = (const float*)d_in[0];   // 1024 x 50000
    const float* weight = (const float*)d_in[1];   // 50000 x 300
    float* out = (float*)d_out;                    // 1024 x 300

    float* Cacc = (float*)d_ws;                                  // 1.31 MB
    bf16*  Wt   = (bf16*)((char*)d_ws + (size_t)Mdim * NP * sizeof(float)); // 32 MB

    hipMemsetAsync(Cacc, 0, (size_t)Mdim * NP * sizeof(float), stream);
    transpose_w<<<dim3((Kdim + TK - 1) / TK), dim3(256), 0, stream>>>(weight, Wt);
    gemm_kernel<<<dim3(MT * SPLIT), dim3(512), 0, stream>>>(labels, Wt, Cacc);
    normalize_k<<<dim3(Mdim), dim3(320), 0, stream>>>(Cacc, out);
}

// Round 3
// 388.010 us; speedup vs baseline: 1.0906x; 1.0102x over previous
//
#include <hip/hip_runtime.h>
#include <hip/hip_bf16.h>
#include <math.h>

// attr = labels(1024x50000 f32) @ weight(50000x300 f32); out = attr/(||attr||+1e-7)
// k1: weight -> Wt[n][k] bf16 (n padded to 320) -- LDS transpose
// k2: split-K MFMA GEMM, BM=64 BN=320 BK=64, 2 blocks/CU for latency hiding,
//     reg-prefetch pipeline, fp32 atomic partials
// k3: row L2 normalize
typedef __bf16 bf16;
typedef bf16 bf16x8 __attribute__((ext_vector_type(8)));
typedef float f32x4 __attribute__((ext_vector_type(4)));

constexpr int Mdim = 1024;
constexpr int Kdim = 50000;
constexpr int Ndim = 300;
constexpr int NP   = 320;

constexpr int BM = 64, BN = 320, BK = 64;
constexpr int BKP = 72;            // LDS k-stride (bf16), pad vs 32-bank aliasing
constexpr int MT = Mdim / BM;      // 16 m-tiles
constexpr int SPLIT = 32;          // grid = 512 = 2 blocks/CU (LDS 55.3KB -> exactly 2 fit)
constexpr int SEGLEN = 1600;       // 25 BK-iters; last seg 400

__device__ __forceinline__ bf16x8 bzero8() {
    bf16x8 v;
#pragma unroll
    for (int e = 0; e < 8; ++e) v[e] = (bf16)0.0f;
    return v;
}

// ---------------- k1: transpose + convert -----------------------------------
constexpr int TK = 64;
constexpr int TS = 301;            // odd stride -> phase-2 strided reads spread banks
__global__ __launch_bounds__(256) void transpose_w(const float* __restrict__ W,
                                                   bf16* __restrict__ Wt)
{
    __shared__ bf16 tile[TK * TS];
    const int k0 = blockIdx.x * TK;
    const int t  = threadIdx.x;

    for (int c = t; c < 64 * 75; c += 256) {
        const int kk = c / 75;
        const int ch = c % 75;
        const int k  = k0 + kk;
        float4 v = make_float4(0.f, 0.f, 0.f, 0.f);
        if (k < Kdim) v = *(const float4*)(W + (size_t)k * Ndim + ch * 4);
        bf16* p = &tile[kk * TS + ch * 4];
        p[0] = (bf16)v.x; p[1] = (bf16)v.y; p[2] = (bf16)v.z; p[3] = (bf16)v.w;
    }
    __syncthreads();
    for (int c = t; c < NP * 8; c += 256) {
        const int n  = c >> 3;
        const int ch = c & 7;
        const int k  = k0 + ch * 8;
        if (k + 8 <= Kdim) {
            bf16x8 v = bzero8();
            if (n < Ndim) {
#pragma unroll
                for (int j = 0; j < 8; ++j) v[j] = tile[(ch * 8 + j) * TS + n];
            }
            *(bf16x8*)(Wt + (size_t)n * Kdim + k) = v;
        }
    }
}

// ---------------- k2: split-K MFMA GEMM -------------------------------------
__global__ __launch_bounds__(512, 4) void gemm_kernel(const float* __restrict__ A,
                                                      const bf16* __restrict__ Wt,
                                                      float* __restrict__ Cacc)
{
    __shared__ bf16 As[BM * BKP];   //  9216 B
    __shared__ bf16 Bs[BN * BKP];   // 46080 B   (55296 total -> 2 blocks/CU)

    const int bx   = blockIdx.x;
    const int mt   = bx & (MT - 1);
    const int ks   = bx >> 4;
    const int m0   = mt * BM;
    const int kbeg = ks * SEGLEN;
    const int kend = min(kbeg + SEGLEN, Kdim);

    const int t    = threadIdx.x;
    const int lane = t & 63;
    const int wave = t >> 6;         // 0..7 as 2m x 4n
    const int wm   = wave >> 2;      // m offset wm*32
    const int wn   = wave & 3;       // n offset wn*80
    const int lm   = lane & 15;
    const int lq   = lane >> 4;

    // A staging: thread -> row t>>3 (0..63), 8 consecutive k at (t&7)*8
    const int arow = t >> 3;
    const int acol = (t & 7) * 8;
    const float* aptr = A + (size_t)(m0 + arow) * Kdim;

    float4 af[2];
    bf16x8 bfr[5];

    auto load_tiles = [&](int k0) {
        const int k = k0 + acol;
        if (k + 8 <= kend) {
            af[0] = *(const float4*)(aptr + k);
            af[1] = *(const float4*)(aptr + k + 4);
        } else {
            af[0] = make_float4(0.f, 0.f, 0.f, 0.f);
            af[1] = make_float4(0.f, 0.f, 0.f, 0.f);
        }
#pragma unroll
        for (int i = 0; i < 5; ++i) {
            const int c = t + 512 * i;
            const int brow = c >> 3;
            const int bcol = (c & 7) * 8;
            const int kk = k0 + bcol;
            bfr[i] = (kk + 8 <= kend) ? *(const bf16x8*)(Wt + (size_t)brow * Kdim + kk)
                                      : bzero8();
        }
    };
    auto store_tiles = [&]() {
        bf16x8 v;
        v[0]=(bf16)af[0].x; v[1]=(bf16)af[0].y; v[2]=(bf16)af[0].z; v[3]=(bf16)af[0].w;
        v[4]=(bf16)af[1].x; v[5]=(bf16)af[1].y; v[6]=(bf16)af[1].z; v[7]=(bf16)af[1].w;
        *(bf16x8*)(&As[arow * BKP + acol]) = v;
#pragma unroll
        for (int i = 0; i < 5; ++i) {
            const int c = t + 512 * i;
            const int brow = c >> 3;
            const int bcol = (c & 7) * 8;
            *(bf16x8*)(&Bs[brow * BKP + bcol]) = bfr[i];
        }
    };

    f32x4 acc[2][5] = {};

    load_tiles(kbeg);
    for (int k0 = kbeg; k0 < kend; k0 += BK) {
        store_tiles();               // waits vmcnt, regs -> LDS
        __syncthreads();
        if (k0 + BK < kend) load_tiles(k0 + BK);   // in flight across MFMA phase
#pragma unroll
        for (int s = 0; s < 2; ++s) {
            bf16x8 a[2], b[5];
#pragma unroll
            for (int i = 0; i < 2; ++i)
                a[i] = *(const bf16x8*)(&As[(wm * 32 + i * 16 + lm) * BKP + s * 32 + lq * 8]);
#pragma unroll
            for (int j = 0; j < 5; ++j)
                b[j] = *(const bf16x8*)(&Bs[(wn * 80 + j * 16 + lm) * BKP + s * 32 + lq * 8]);
#pragma unroll
            for (int i = 0; i < 2; ++i)
#pragma unroll
                for (int j = 0; j < 5; ++j)
                    acc[i][j] = __builtin_amdgcn_mfma_f32_16x16x32_bf16(a[i], b[j], acc[i][j], 0, 0, 0);
        }
        __syncthreads();
    }

    // C/D layout: col=lane&15, row=(lane>>4)*4+r  [learn_hip m89]
    const int col0 = wn * 80 + lm;
    const int row0 = m0 + wm * 32 + lq * 4;
#pragma unroll
    for (int i = 0; i < 2; ++i)
#pragma unroll
        for (int j = 0; j < 5; ++j)
#pragma unroll
            for (int r = 0; r < 4; ++r)
                atomicAdd(&Cacc[(size_t)(row0 + i * 16 + r) * NP + col0 + j * 16],
                          acc[i][j][r]);
}

// ---------------- k3: row L2 normalize --------------------------------------
__global__ __launch_bounds__(320) void normalize_k(const float* __restrict__ Cacc,
                                                   float* __restrict__ out)
{
    const int b = blockIdx.x;
    const int t = threadIdx.x;
    float v = 0.f;
    if (t < Ndim) v = Cacc[(size_t)b * NP + t];
    float ss = v * v;
#pragma unroll
    for (int o = 32; o > 0; o >>= 1) ss += __shfl_down(ss, o, 64);
    __shared__ float wsum[5];
    __shared__ float scale;
    if ((t & 63) == 0) wsum[t >> 6] = ss;
    __syncthreads();
    if (t == 0) {
        float s = wsum[0] + wsum[1] + wsum[2] + wsum[3] + wsum[4];
        scale = 1.0f / (sqrtf(s) + 1e-7f);
    }
    __syncthreads();
    if (t < Ndim) out[(size_t)b * Ndim + t] = v * scale;
}

// ---------------- launch ----------------------------------------------------
extern "C" void kernel_launch(void* const* d_in, const int* in_sizes, int n_in,
                              void* d_out, int out_size, void* d_ws, size_t ws_size,
                              hipStream_t stream)
{
    const float* labels = (const float*)d_in[0];   // 1024 x 50000
    const float* weight = (const float*)d_in[1];   // 50000 x 300
    float* out = (float*)d_out;                    // 1024 x 300

    float* Cacc = (float*)d_ws;                                  // 1.31 MB
    bf16*  Wt   = (bf16*)((char*)d_ws + (size_t)Mdim * NP * sizeof(float)); // 32 MB

    hipMemsetAsync(Cacc, 0, (size_t)Mdim * NP * sizeof(float), stream);
    transpose_w<<<dim3((Kdim + TK - 1) / TK), dim3(256), 0, stream>>>(weight, Wt);
    gemm_kernel<<<dim3(MT * SPLIT), dim3(512), 0, stream>>>(labels, Wt, Cacc);
    normalize_k<<<dim3(Mdim), dim3(320), 0, stream>>>(Cacc, out);
}

// Round 4
// 378.952 us; speedup vs baseline: 1.1166x; 1.0239x over previous
//
#include <hip/hip_runtime.h>
#include <hip/hip_bf16.h>
#include <math.h>

// attr = labels(1024x50000 f32) @ weight(50000x300 f32); out = attr/(||attr||+1e-7)
// k1: weight -> Wt[n][k] bf16 (n padded to 320) -- LDS transpose
// k2: split-K MFMA GEMM, BM=64 BN=320 BK=64, NON-ATOMIC per-split partials
//     (atomic fallback if ws too small)
// k3: reduce partials over splits + row L2 normalize (fused)
typedef __bf16 bf16;
typedef bf16 bf16x8 __attribute__((ext_vector_type(8)));
typedef float f32x4 __attribute__((ext_vector_type(4)));

constexpr int Mdim = 1024;
constexpr int Kdim = 50000;
constexpr int Ndim = 300;
constexpr int NP   = 320;

constexpr int BM = 64, BN = 320, BK = 64;
constexpr int BKP = 72;            // LDS k-stride (bf16)
constexpr int MT = Mdim / BM;      // 16 m-tiles

__device__ __forceinline__ bf16x8 bzero8() {
    bf16x8 v;
#pragma unroll
    for (int e = 0; e < 8; ++e) v[e] = (bf16)0.0f;
    return v;
}

// ---------------- k1: transpose + convert -----------------------------------
constexpr int TK = 64;
constexpr int TS = 301;
__global__ __launch_bounds__(256) void transpose_w(const float* __restrict__ W,
                                                   bf16* __restrict__ Wt)
{
    __shared__ bf16 tile[TK * TS];
    const int k0 = blockIdx.x * TK;
    const int t  = threadIdx.x;

    for (int c = t; c < 64 * 75; c += 256) {
        const int kk = c / 75;
        const int ch = c % 75;
        const int k  = k0 + kk;
        float4 v = make_float4(0.f, 0.f, 0.f, 0.f);
        if (k < Kdim) v = *(const float4*)(W + (size_t)k * Ndim + ch * 4);
        bf16* p = &tile[kk * TS + ch * 4];
        p[0] = (bf16)v.x; p[1] = (bf16)v.y; p[2] = (bf16)v.z; p[3] = (bf16)v.w;
    }
    __syncthreads();
    for (int c = t; c < NP * 8; c += 256) {
        const int n  = c >> 3;
        const int ch = c & 7;
        const int k  = k0 + ch * 8;
        if (k + 8 <= Kdim) {
            bf16x8 v = bzero8();
            if (n < Ndim) {
#pragma unroll
                for (int j = 0; j < 8; ++j) v[j] = tile[(ch * 8 + j) * TS + n];
            }
            *(bf16x8*)(Wt + (size_t)n * Kdim + k) = v;
        }
    }
}

// ---------------- k2: split-K MFMA GEMM -------------------------------------
// ATOMIC=false: out = P, partials at P[ks][Mdim][NP] (plain stores)
// ATOMIC=true : out = Cacc[Mdim][NP] (atomicAdd), Cacc pre-zeroed
template<int SPLIT, int SEGLEN, bool ATOMIC>
__global__ __launch_bounds__(512, 4) void gemm_kernel(const float* __restrict__ A,
                                                      const bf16* __restrict__ Wt,
                                                      float* __restrict__ out)
{
    __shared__ bf16 As[BM * BKP];   //  9216 B
    __shared__ bf16 Bs[BN * BKP];   // 46080 B  (55296 -> 2 blocks/CU)

    const int bx   = blockIdx.x;
    const int mt   = bx & (MT - 1);
    const int ks   = bx >> 4;
    const int m0   = mt * BM;
    const int kbeg = ks * SEGLEN;
    const int kend = min(kbeg + SEGLEN, Kdim);

    const int t    = threadIdx.x;
    const int lane = t & 63;
    const int wave = t >> 6;         // 0..7 as 2m x 4n
    const int wm   = wave >> 2;
    const int wn   = wave & 3;
    const int lm   = lane & 15;
    const int lq   = lane >> 4;

    const int arow = t >> 3;
    const int acol = (t & 7) * 8;
    const float* aptr = A + (size_t)(m0 + arow) * Kdim;

    float4 af[2];
    bf16x8 bfr[5];

    auto load_tiles = [&](int k0) {
        const int k = k0 + acol;
        if (k + 8 <= kend) {
            af[0] = *(const float4*)(aptr + k);
            af[1] = *(const float4*)(aptr + k + 4);
        } else {
            af[0] = make_float4(0.f, 0.f, 0.f, 0.f);
            af[1] = make_float4(0.f, 0.f, 0.f, 0.f);
        }
#pragma unroll
        for (int i = 0; i < 5; ++i) {
            const int c = t + 512 * i;
            const int brow = c >> 3;
            const int bcol = (c & 7) * 8;
            const int kk = k0 + bcol;
            bfr[i] = (kk + 8 <= kend) ? *(const bf16x8*)(Wt + (size_t)brow * Kdim + kk)
                                      : bzero8();
        }
    };
    auto store_tiles = [&]() {
        bf16x8 v;
        v[0]=(bf16)af[0].x; v[1]=(bf16)af[0].y; v[2]=(bf16)af[0].z; v[3]=(bf16)af[0].w;
        v[4]=(bf16)af[1].x; v[5]=(bf16)af[1].y; v[6]=(bf16)af[1].z; v[7]=(bf16)af[1].w;
        *(bf16x8*)(&As[arow * BKP + acol]) = v;
#pragma unroll
        for (int i = 0; i < 5; ++i) {
            const int c = t + 512 * i;
            const int brow = c >> 3;
            const int bcol = (c & 7) * 8;
            *(bf16x8*)(&Bs[brow * BKP + bcol]) = bfr[i];
        }
    };

    f32x4 acc[2][5] = {};

    load_tiles(kbeg);
    for (int k0 = kbeg; k0 < kend; k0 += BK) {
        store_tiles();
        __syncthreads();
        if (k0 + BK < kend) load_tiles(k0 + BK);
#pragma unroll
        for (int s = 0; s < 2; ++s) {
            bf16x8 a[2], b[5];
#pragma unroll
            for (int i = 0; i < 2; ++i)
                a[i] = *(const bf16x8*)(&As[(wm * 32 + i * 16 + lm) * BKP + s * 32 + lq * 8]);
#pragma unroll
            for (int j = 0; j < 5; ++j)
                b[j] = *(const bf16x8*)(&Bs[(wn * 80 + j * 16 + lm) * BKP + s * 32 + lq * 8]);
#pragma unroll
            for (int i = 0; i < 2; ++i)
#pragma unroll
                for (int j = 0; j < 5; ++j)
                    acc[i][j] = __builtin_amdgcn_mfma_f32_16x16x32_bf16(a[i], b[j], acc[i][j], 0, 0, 0);
        }
        __syncthreads();
    }

    // C/D layout: col=lane&15, row=(lane>>4)*4+r  [learn_hip m89]
    const int col0 = wn * 80 + lm;
    const int rloc = wm * 32 + lq * 4;
    if (ATOMIC) {
#pragma unroll
        for (int i = 0; i < 2; ++i)
#pragma unroll
            for (int j = 0; j < 5; ++j)
#pragma unroll
                for (int r = 0; r < 4; ++r)
                    atomicAdd(&out[(size_t)(m0 + rloc + i * 16 + r) * NP + col0 + j * 16],
                              acc[i][j][r]);
    } else {
        float* P = out + (size_t)ks * Mdim * NP;
#pragma unroll
        for (int i = 0; i < 2; ++i)
#pragma unroll
            for (int j = 0; j < 5; ++j)
#pragma unroll
                for (int r = 0; r < 4; ++r)
                    P[(size_t)(m0 + rloc + i * 16 + r) * NP + col0 + j * 16] = acc[i][j][r];
    }
}

// ---------------- k3a: reduce partials + L2 normalize (partial path) --------
__global__ __launch_bounds__(320) void reduce_norm_k(const float* __restrict__ P,
                                                     float* __restrict__ out,
                                                     int split)
{
    const int b = blockIdx.x;
    const int t = threadIdx.x;
    float v = 0.f;
    for (int ks = 0; ks < split; ++ks)
        v += P[((size_t)ks * Mdim + b) * NP + t];     // coalesced per ks
    float ss = v * v;
#pragma unroll
    for (int o = 32; o > 0; o >>= 1) ss += __shfl_down(ss, o, 64);
    __shared__ float wsum[5];
    __shared__ float scale;
    if ((t & 63) == 0) wsum[t >> 6] = ss;
    __syncthreads();
    if (t == 0) {
        float s = wsum[0] + wsum[1] + wsum[2] + wsum[3] + wsum[4];
        scale = 1.0f / (sqrtf(s) + 1e-7f);
    }
    __syncthreads();
    if (t < Ndim) out[(size_t)b * Ndim + t] = v * scale;
}

// ---------------- k3b: normalize only (atomic fallback path) ----------------
__global__ __launch_bounds__(320) void normalize_k(const float* __restrict__ Cacc,
                                                   float* __restrict__ out)
{
    const int b = blockIdx.x;
    const int t = threadIdx.x;
    float v = 0.f;
    if (t < Ndim) v = Cacc[(size_t)b * NP + t];
    float ss = v * v;
#pragma unroll
    for (int o = 32; o > 0; o >>= 1) ss += __shfl_down(ss, o, 64);
    __shared__ float wsum[5];
    __shared__ float scale;
    if ((t & 63) == 0) wsum[t >> 6] = ss;
    __syncthreads();
    if (t == 0) {
        float s = wsum[0] + wsum[1] + wsum[2] + wsum[3] + wsum[4];
        scale = 1.0f / (sqrtf(s) + 1e-7f);
    }
    __syncthreads();
    if (t < Ndim) out[(size_t)b * Ndim + t] = v * scale;
}

// ---------------- launch ----------------------------------------------------
extern "C" void kernel_launch(void* const* d_in, const int* in_sizes, int n_in,
                              void* d_out, int out_size, void* d_ws, size_t ws_size,
                              hipStream_t stream)
{
    const float* labels = (const float*)d_in[0];   // 1024 x 50000
    const float* weight = (const float*)d_in[1];   // 50000 x 300
    float* out = (float*)d_out;                    // 1024 x 300

    bf16* Wt = (bf16*)d_ws;                                   // 32.0 MB at offset 0
    const size_t wtBytes  = (size_t)NP * Kdim * sizeof(bf16); // 32,000,000
    float* aux = (float*)((char*)d_ws + wtBytes);
    const size_t perSplit = (size_t)Mdim * NP * sizeof(float); // 1.31 MB

    transpose_w<<<dim3((Kdim + TK - 1) / TK), dim3(256), 0, stream>>>(weight, Wt);

    if (ws_size >= wtBytes + 32 * perSplit) {
        // partial path, SPLIT=32 (SEGLEN=1600, grid 512 = 2 blocks/CU)
        gemm_kernel<32, 1600, false><<<dim3(MT * 32), dim3(512), 0, stream>>>(labels, Wt, aux);
        reduce_norm_k<<<dim3(Mdim), dim3(320), 0, stream>>>(aux, out, 32);
    } else if (ws_size >= wtBytes + 16 * perSplit) {
        // partial path, SPLIT=16 (SEGLEN=3136, grid 256)
        gemm_kernel<16, 3136, false><<<dim3(MT * 16), dim3(512), 0, stream>>>(labels, Wt, aux);
        reduce_norm_k<<<dim3(Mdim), dim3(320), 0, stream>>>(aux, out, 16);
    } else {
        // atomic fallback (needs 33.3 MB)
        hipMemsetAsync(aux, 0, perSplit, stream);
        gemm_kernel<32, 1600, true><<<dim3(MT * 32), dim3(512), 0, stream>>>(labels, Wt, aux);
        normalize_k<<<dim3(Mdim), dim3(320), 0, stream>>>(aux, out);
    }
}